// Round 10
// baseline (458.651 us; speedup 1.0000x reference)
//
#include <hip/hip_runtime.h>
#include <math.h>

#define Bn 4
#define Ln 1024
#define Dn 128
#define Hn 8
#define Gn 64
#define NITERS 4

typedef _Float16 f16;
typedef _Float16 half8 __attribute__((ext_vector_type(8)));
typedef _Float16 half4v __attribute__((ext_vector_type(4)));
typedef float floatx4 __attribute__((ext_vector_type(4)));

#define WPAD 136   // f16 stride for uv_kernel row-major tiles

#define MFMA(a, b, c) __builtin_amdgcn_mfma_f32_16x16x32_f16((a), (b), (c), 0, 0, 0)

union h8u { half8 h; half4v v[2]; };

// async global->LDS, 16B per lane; dest = lds_base + lane*16 (wave-uniform base)
__device__ __forceinline__ void gl_lds16(const f16* g, f16* l) {
    __builtin_amdgcn_global_load_lds(
        (const __attribute__((address_space(1))) void*)(g),
        (__attribute__((address_space(3))) void*)(l),
        16, 0, 0);
}

// 512-thread staging: one 64x128 tile (row stride Dn) into UsB and one
// 128x64 tile (row stride sb) into UbB, XOR-swizzled (16B-group g stored at
// g^(row&7)). Each thread issues 4 gl_lds16.
__device__ __forceinline__ void issue_tiles8(const f16* us, const f16* ub, int sb,
                                             f16* UsB, f16* UbB, int w, int l) {
    #pragma unroll
    for (int k = 0; k < 2; k++) {
        int c = w * 2 + k;
        {   // Us: 64 rows x 16 groups
            int r = c * 4 + (l >> 4); int g = (l & 15) ^ (r & 7);
            gl_lds16(us + (size_t)r * Dn + g * 8, UsB + c * 512);
        }
        {   // Ub: 128 rows x 8 groups
            int r = c * 8 + (l >> 3); int g = (l & 7) ^ (r & 7);
            gl_lds16(ub + (size_t)r * sb + g * 8, UbB + c * 512);
        }
    }
}

// ---------------- repack ternary/global into f16 per-head layouts -----------
// Gpt columns pre-permuted by pi: pos(g) = (g>>5)*32+((g>>2)&3)*8+((g>>4)&1)*4+(g&3)
__global__ void repack_kernel(const float* __restrict__ ter, const float* __restrict__ glb,
                              f16* __restrict__ TpA, f16* __restrict__ TpB,
                              f16* __restrict__ GpA, f16* __restrict__ Gpt) {
    int idx = blockIdx.x * 256 + threadIdx.x;
    if (idx < Dn * Dn * Hn) {
        int h = idx % Hn; int b = (idx / Hn) % Dn; int a = idx / (Hn * Dn);
        f16 v = (f16)ter[idx];
        TpA[((size_t)h * Dn + a) * Dn + b] = v;
        TpB[((size_t)h * Dn + b) * Dn + a] = v;
    }
    if (idx < Gn * Dn * Hn) {
        int h = idx % Hn; int a = (idx / Hn) % Dn; int g = idx / (Hn * Dn);
        f16 v = (f16)glb[idx];
        GpA[((size_t)h * Gn + g) * Dn + a] = v;
        int pos = ((g >> 5) << 5) | (((g >> 2) & 3) << 3) | (((g >> 4) & 1) << 2) | (g & 3);
        Gpt[((size_t)h * Dn + a) * Gn + pos] = v;
    }
}

// ---------------- row softmax over D=128 (fp32 in, f16 out) -----------------
__global__ void softmax_rows_kernel(const float* __restrict__ in, f16* __restrict__ out) {
    int row = blockIdx.x;
    int t = threadIdx.x;  // 0..127
    __shared__ float red[2];
    float v = in[(size_t)row * Dn + t];
    float m = v;
    #pragma unroll
    for (int off = 1; off < 64; off <<= 1) m = fmaxf(m, __shfl_xor(m, off, 64));
    if ((t & 63) == 0) red[t >> 6] = m;
    __syncthreads();
    m = fmaxf(red[0], red[1]);
    float e = __expf(v - m);
    float s = e;
    #pragma unroll
    for (int off = 1; off < 64; off <<= 1) s += __shfl_xor(s, off, 64);
    __syncthreads();
    if ((t & 63) == 0) red[t >> 6] = s;
    __syncthreads();
    s = red[0] + red[1];
    out[(size_t)row * Dn + t] = (f16)(e / s);
}

// ---------------- U/V projection via MFMA ----------------------------------
// Ut/Vt columns stored pi-permuted within each 64-tile. U/Ut carry a -64
// bias on masked-j rows (Qz rows sum to 1 -> scores shift -64 -> exp ~= 0).
__launch_bounds__(256, 4)
__global__ void uv_kernel(const f16* __restrict__ Qz, const f16* __restrict__ TpA,
                          const f16* __restrict__ TpB, const int* __restrict__ mask,
                          f16* __restrict__ U, f16* __restrict__ Ut, f16* __restrict__ Vt) {
    int bx = blockIdx.x;  // 16 j-strips of 64
    int h  = blockIdx.y;
    int n  = blockIdx.z;
    int t  = threadIdx.x;
    int w = t >> 6, l = t & 63, m = l & 15, q = l >> 4;

    __shared__ __align__(16) f16 Ts[128 * WPAD];

    int jrow = bx * 64 + w * 16 + m;
    const f16* qbase = Qz + ((size_t)n * Ln + jrow) * Dn;
    half8 aq[4];
    #pragma unroll
    for (int ks = 0; ks < 4; ks++)
        aq[ks] = *(const half8*)(qbase + ks * 32 + q * 8);

    size_t hoff = (size_t)(n * Hn + h);
    int jr0 = bx * 64 + w * 16 + 4 * q;
    int jrp = bx * 64 + (w >> 1) * 32 + q * 8 + (w & 1) * 4;  // pi^-1 position

    float bias[4];
    #pragma unroll
    for (int reg = 0; reg < 4; reg++)
        bias[reg] = mask[n * Ln + jr0 + reg] ? 0.f : -64.f;

    // ---- pass 1: U = Qz * TpA^T (biased) ----
    {
        const f16* src = TpA + (size_t)h * Dn * Dn;
        for (int ii = 0; ii < 8; ii++) {
            int idx = t + 256 * ii; int r = idx >> 4, c = idx & 15;
            *(float4*)&Ts[r * WPAD + c * 8] = *(const float4*)(src + (size_t)r * Dn + c * 8);
        }
        __syncthreads();
        #pragma unroll
        for (int ct = 0; ct < 8; ct++) {
            floatx4 acc = {0.f, 0.f, 0.f, 0.f};
            #pragma unroll
            for (int ks = 0; ks < 4; ks++) {
                half8 b = *(const half8*)&Ts[(ct * 16 + m) * WPAD + ks * 32 + q * 8];
                acc = MFMA(aq[ks], b, acc);
            }
            f16* ub = U + (hoff * Ln + jr0) * Dn + ct * 16 + m;
            half4v pk;
            #pragma unroll
            for (int reg = 0; reg < 4; reg++) {
                f16 v = (f16)(acc[reg] + bias[reg]);
                ub[(size_t)reg * Dn] = v;
                pk[reg] = v;
            }
            *(half4v*)(Ut + (hoff * Dn + ct * 16 + m) * Ln + jrp) = pk;
        }
        __syncthreads();
    }
    // ---- pass 2: V = Qz * TpB^T, stored transposed (pi-permuted, unbiased) --
    {
        const f16* src = TpB + (size_t)h * Dn * Dn;
        for (int ii = 0; ii < 8; ii++) {
            int idx = t + 256 * ii; int r = idx >> 4, c = idx & 15;
            *(float4*)&Ts[r * WPAD + c * 8] = *(const float4*)(src + (size_t)r * Dn + c * 8);
        }
        __syncthreads();
        #pragma unroll
        for (int ct = 0; ct < 8; ct++) {
            floatx4 acc = {0.f, 0.f, 0.f, 0.f};
            #pragma unroll
            for (int ks = 0; ks < 4; ks++) {
                half8 b = *(const half8*)&Ts[(ct * 16 + m) * WPAD + ks * 32 + q * 8];
                acc = MFMA(aq[ks], b, acc);
            }
            half4v pk = { (f16)acc[0], (f16)acc[1], (f16)acc[2], (f16)acc[3] };
            *(half4v*)(Vt + (hoff * Dn + ct * 16 + m) * Ln + jrp) = pk;
        }
    }
}

// ---------------- msg_i + msg_g: BM=128, j-half split, 2 blocks/CU ----------
// Block = (it, jhalf, h, n); owns 128 i and HALF the j-range (8 tiles, +G on
// jhalf=1). Wave w = (ih = w>>1 owning 32 i, kw = w&1 j-sub-half). Inner loop
// identical to R9 (verified). Writes UNNORMALIZED partial Mi[jhalf] (f16) and
// partial row-sums rowLp[jhalf] (f32); normalization happens in combine/msgj.
// LDS 65KB -> 2 blocks/CU = 4 waves/SIMD at HALF of R6's LDS traffic.
__launch_bounds__(512, 2)
__global__ void msgi_kernel(const f16* __restrict__ Qz, const f16* __restrict__ U,
                            const f16* __restrict__ Ut, const f16* __restrict__ GpA,
                            const f16* __restrict__ Gpt,
                            f16* __restrict__ Mi, float* __restrict__ rowLp) {
    int p = blockIdx.x;              // XCD p%8 owns head h
    int h     = p & 7;
    int jhalf = (p >> 3) & 1;
    int it    = (p >> 4) & 7;
    int n     = p >> 7;
    int t = threadIdx.x;
    int w = t >> 6, l = t & 63, m = l & 15, q = l >> 4;
    int ih = w >> 1;   // i 32-row group
    int kw = w & 1;    // j-sub-half of the reduction

    __shared__ __align__(16) f16 Us[2][64 * 128];
    __shared__ __align__(16) f16 Ub[2][128 * 64];
    __shared__ float lred[2][128];

    size_t hoff = (size_t)(n * Hn + h);

    // resident B-frags: Qz rows of this wave's 32 i
    half8 bq[2][4];
    #pragma unroll
    for (int ib = 0; ib < 2; ib++) {
        const f16* qr = Qz + ((size_t)n * Ln + it * 128 + ih * 32 + ib * 16 + m) * Dn;
        #pragma unroll
        for (int ks = 0; ks < 4; ks++)
            bq[ib][ks] = *(const half8*)(qr + ks * 32 + q * 8);
    }

    float lacc[2] = {0.f, 0.f};
    floatx4 Oacc[2][8];
    #pragma unroll
    for (int ib = 0; ib < 2; ib++)
        #pragma unroll
        for (int at = 0; at < 8; at++) Oacc[ib][at] = (floatx4){0.f, 0.f, 0.f, 0.f};

    int NS = 8 + jhalf;   // jhalf=1 also runs the G step
    int jt0 = jhalf * 8;

    issue_tiles8(U + (hoff * Ln + (size_t)jt0 * 64) * Dn,
                 Ut + hoff * Dn * Ln + jt0 * 64, Ln, Us[0], Ub[0], w, l);
    __syncthreads();

    for (int s = 0; s < NS; s++) {
        int cur = s & 1, nxt = cur ^ 1;
        if (s + 1 < NS) {
            int jt1 = jt0 + s + 1;
            const f16 *us, *ub; int sb;
            if (jt1 < 16) {
                us = U + (hoff * Ln + (size_t)jt1 * 64) * Dn;
                ub = Ut + hoff * Dn * Ln + jt1 * 64;
                sb = Ln;
            } else {
                us = GpA + (size_t)h * Gn * Dn;
                ub = Gpt + (size_t)h * Dn * Gn;
                sb = Gn;
            }
            issue_tiles8(us, ub, sb, Us[nxt], Ub[nxt], w, l);
        }
        // scores S^T[j][i] for jb = 2kw+jb2 (32 j) x this wave's 32 i
        half4v hv[2][2];
        #pragma unroll
        for (int jb2 = 0; jb2 < 2; jb2++) {
            int jb = kw * 2 + jb2;
            int r0 = jb * 16 + m;
            half8 au[4];
            #pragma unroll
            for (int ks = 0; ks < 4; ks++)
                au[ks] = *(const half8*)&Us[cur][((size_t)r0 << 7) + ((((ks << 2) + q)) ^ (r0 & 7)) * 8];
            #pragma unroll
            for (int ib = 0; ib < 2; ib++) {
                floatx4 s2 = {0.f, 0.f, 0.f, 0.f};
                #pragma unroll
                for (int ks = 0; ks < 4; ks++) s2 = MFMA(au[ks], bq[ib][ks], s2);
                half4v pk;
                #pragma unroll
                for (int reg = 0; reg < 4; reg++) {
                    float p2 = __expf(fminf(s2[reg], 11.f));   // masked j: bias -> ~0
                    lacc[ib] += p2;
                    pk[reg] = (f16)p2;
                }
                hv[jb2][ib] = pk;
            }
        }
        // PV (kst = kw): A = own packed scores (pi k-order), B from Ub[cur]
        half8 aP[2];
        #pragma unroll
        for (int ib = 0; ib < 2; ib++) {
            h8u u; u.v[0] = hv[0][ib]; u.v[1] = hv[1][ib];
            aP[ib] = u.h;
        }
        #pragma unroll
        for (int at = 0; at < 8; at++) {
            int r0 = at * 16 + m;
            half8 bU = *(const half8*)&Ub[cur][((size_t)r0 << 6) + ((((kw << 2) + q)) ^ (r0 & 7)) * 8];
            #pragma unroll
            for (int ib = 0; ib < 2; ib++)
                Oacc[ib][at] = MFMA(aP[ib], bU, Oacc[ib][at]);
        }
        __syncthreads();  // drains nxt DMA; releases cur for s+2
    }

    // ---- epilogue: partial row sums + cross-kw Oacc reduce ----
    #pragma unroll
    for (int ib = 0; ib < 2; ib++) {
        float v = lacc[ib];
        v += __shfl_xor(v, 16, 64);
        v += __shfl_xor(v, 32, 64);
        lacc[ib] = v;
    }
    if (q == 0) {
        lred[kw][ih * 32 + m]      = lacc[0];
        lred[kw][ih * 32 + 16 + m] = lacc[1];
    }
    __syncthreads();
    if (t < 128)
        rowLp[((size_t)jhalf * Bn * Hn + hoff) * Ln + it * 128 + t] = lred[0][t] + lred[1][t];
    // Us flat = 8192 floats -> ih 0,1 slabs of 4096; Ub -> ih 2,3.
    float* od = (ih < 2) ? ((float*)Us + (size_t)ih * 4096)
                         : ((float*)Ub + (size_t)(ih - 2) * 4096);
    od += (size_t)l * 64;
    if (kw == 1) {
        #pragma unroll
        for (int c = 0; c < 16; c++)
            *(floatx4*)(od + c * 4) = Oacc[c >> 3][c & 7];
    }
    __syncthreads();
    if (kw == 0) {
        f16* Mo = Mi + (((size_t)jhalf * Bn * Hn + hoff) * Ln + (size_t)it * 128) * Dn;
        #pragma unroll
        for (int ib = 0; ib < 2; ib++)
            #pragma unroll
            for (int reg = 0; reg < 4; reg++) {
                int row = ih * 32 + ib * 16 + 4 * q + reg;
                #pragma unroll
                for (int at = 0; at < 8; at++) {
                    float v = Oacc[ib][at][reg] + od[(ib * 8 + at) * 4 + reg];
                    Mo[(size_t)row * Dn + at * 16 + m] = (f16)v;   // unnormalized
                }
            }
    }
}

// ---------------- msg_j: BM=128, i-half split, 2 blocks/CU ------------------
// Block = (jt, ihalf, h, n); owns 128 j and half the i-range. linv computed
// from the two rowLp partials (+ i-mask). Output: plain store to Mj[ihalf].
__launch_bounds__(512, 2)
__global__ void msgj_kernel(const f16* __restrict__ Qz, const f16* __restrict__ U,
                            const f16* __restrict__ Vt, const int* __restrict__ mask,
                            const float* __restrict__ rowLp, f16* __restrict__ Mj) {
    int p = blockIdx.x;              // XCD p%8 owns head h
    int h     = p & 7;
    int ihalf = (p >> 3) & 1;
    int jt    = (p >> 4) & 7;
    int n     = p >> 7;
    int t = threadIdx.x;
    int w = t >> 6, l = t & 63, m = l & 15, q = l >> 4;
    int jh = w >> 1;   // j 32-row group
    int kw = w & 1;    // i-sub-half of the reduction

    __shared__ __align__(16) f16 Qs[2][64 * 128];
    __shared__ __align__(16) f16 Vb[2][128 * 64];
    __shared__ __align__(16) float lvAll[512];

    size_t hoff = (size_t)(n * Hn + h);

    // resident B-frags: U rows of this wave's 32 j (bias carries j-mask)
    half8 bu[2][4];
    #pragma unroll
    for (int jb = 0; jb < 2; jb++) {
        const f16* ur = U + (hoff * Ln + (size_t)jt * 128 + jh * 32 + jb * 16 + m) * Dn;
        #pragma unroll
        for (int ks = 0; ks < 4; ks++)
            bu[jb][ks] = *(const half8*)(ur + ks * 32 + q * 8);
    }

    floatx4 Oacc[2][8];
    #pragma unroll
    for (int jb = 0; jb < 2; jb++)
        #pragma unroll
        for (int bt = 0; bt < 8; bt++) Oacc[jb][bt] = (floatx4){0.f, 0.f, 0.f, 0.f};

    // linv for this block's 512 i rows: 1/(rL0+rL1), i-mask folded
    {
        int gi = ihalf * 512 + t;
        float l0 = rowLp[hoff * Ln + gi];
        float l1 = rowLp[((size_t)Bn * Hn + hoff) * Ln + gi];
        lvAll[t] = mask[n * Ln + gi] ? 1.0f / (l0 + l1) : 0.f;
    }

    int gi0 = ihalf * 8;
    issue_tiles8(Qz + ((size_t)n * Ln + (size_t)gi0 * 64) * Dn,
                 Vt + hoff * Dn * Ln + gi0 * 64, Ln, Qs[0], Vb[0], w, l);
    __syncthreads();

    for (int s = 0; s < 8; s++) {
        int cur = s & 1, nxt = cur ^ 1;
        if (s + 1 < 8) {
            int gi1 = gi0 + s + 1;
            issue_tiles8(Qz + ((size_t)n * Ln + (size_t)gi1 * 64) * Dn,
                         Vt + hoff * Dn * Ln + gi1 * 64, Ln, Qs[nxt], Vb[nxt], w, l);
        }
        // scores S[i][j] for ibt = 2kw+ib2 (32 i) x this wave's 32 j
        half4v hv[2][2];
        #pragma unroll
        for (int ib2 = 0; ib2 < 2; ib2++) {
            int ibt = kw * 2 + ib2;
            int r0 = ibt * 16 + m;
            half8 aq2[4];
            #pragma unroll
            for (int ks = 0; ks < 4; ks++)
                aq2[ks] = *(const half8*)&Qs[cur][((size_t)r0 << 7) + ((((ks << 2) + q)) ^ (r0 & 7)) * 8];
            float4 lv = *(const float4*)&lvAll[s * 64 + ibt * 16 + 4 * q];
            float lv4[4] = { lv.x, lv.y, lv.z, lv.w };
            #pragma unroll
            for (int jb = 0; jb < 2; jb++) {
                floatx4 s2 = {0.f, 0.f, 0.f, 0.f};
                #pragma unroll
                for (int ks = 0; ks < 4; ks++) s2 = MFMA(aq2[ks], bu[jb][ks], s2);
                half4v pk;
                #pragma unroll
                for (int reg = 0; reg < 4; reg++)
                    pk[reg] = (f16)(__expf(fminf(s2[reg], 11.f)) * lv4[reg]);
                hv[ib2][jb] = pk;
            }
        }
        // PV (kst = kw): O[j][b] += P'[j][i] * V[i][b]
        half8 aP[2];
        #pragma unroll
        for (int jb = 0; jb < 2; jb++) {
            h8u u; u.v[0] = hv[0][jb]; u.v[1] = hv[1][jb];
            aP[jb] = u.h;
        }
        #pragma unroll
        for (int bt = 0; bt < 8; bt++) {
            int r0 = bt * 16 + m;
            half8 bV = *(const half8*)&Vb[cur][((size_t)r0 << 6) + ((((kw << 2) + q)) ^ (r0 & 7)) * 8];
            #pragma unroll
            for (int jb = 0; jb < 2; jb++)
                Oacc[jb][bt] = MFMA(aP[jb], bV, Oacc[jb][bt]);
        }
        __syncthreads();
    }

    // ---- epilogue: cross-kw reduce, plain store to Mj slab ----
    float* od = (jh < 2) ? ((float*)Qs + (size_t)jh * 4096)
                         : ((float*)Vb + (size_t)(jh - 2) * 4096);
    od += (size_t)l * 64;
    if (kw == 1) {
        #pragma unroll
        for (int c = 0; c < 16; c++)
            *(floatx4*)(od + c * 4) = Oacc[c >> 3][c & 7];
    }
    __syncthreads();
    if (kw == 0) {
        f16* Mo = Mj + (((size_t)ihalf * Bn * Hn + hoff) * Ln + (size_t)jt * 128) * Dn;
        #pragma unroll
        for (int jb = 0; jb < 2; jb++)
            #pragma unroll
            for (int reg = 0; reg < 4; reg++) {
                int row = jh * 32 + jb * 16 + 4 * q + reg;
                #pragma unroll
                for (int bt = 0; bt < 8; bt++) {
                    float v = Oacc[jb][bt][reg] + od[(jb * 8 + bt) * 4 + reg];
                    Mo[(size_t)row * Dn + bt * 16 + m] = (f16)v;
                }
            }
    }
}

// ---------------- fused combine: normalize + sum 4 slabs (+softmax | +mask) -
__global__ void combine_kernel(const float* __restrict__ x, const f16* __restrict__ Mi,
                               const f16* __restrict__ Mj, const float* __restrict__ rowLp,
                               const int* __restrict__ mask, float* __restrict__ out,
                               f16* __restrict__ Qzh, int do_softmax, int do_mask) {
    int row = blockIdx.x;           // B*L rows
    int t = threadIdx.x;            // 0..127
    __shared__ float red[2];
    int n = row >> 10;
    int r = row & 1023;
    const size_t BH = (size_t)Bn * Hn;
    float acc = x[(size_t)row * Dn + t];
    #pragma unroll
    for (int h = 0; h < Hn; h++) {
        size_t hoff = (size_t)n * Hn + h;
        float l0 = rowLp[hoff * Ln + r];
        float l1 = rowLp[(BH + hoff) * Ln + r];
        float linv = 1.0f / (l0 + l1);
        size_t o0 = (hoff * Ln + r) * Dn + t;
        size_t o1 = ((BH + hoff) * Ln + r) * Dn + t;
        float mi = (float)Mi[o0] + (float)Mi[o1];
        float mj = (float)Mj[o0] + (float)Mj[o1];
        acc += mi * linv + mj;
    }
    float o = acc;
    if (do_mask && mask[row] == 0) o = 0.f;
    out[(size_t)row * Dn + t] = o;
    if (do_softmax) {
        float m = acc;
        #pragma unroll
        for (int off = 1; off < 64; off <<= 1) m = fmaxf(m, __shfl_xor(m, off, 64));
        if ((t & 63) == 0) red[t >> 6] = m;
        __syncthreads();
        m = fmaxf(red[0], red[1]);
        float e = __expf(acc - m);
        float s = e;
        #pragma unroll
        for (int off = 1; off < 64; off <<= 1) s += __shfl_xor(s, off, 64);
        __syncthreads();
        if ((t & 63) == 0) red[t >> 6] = s;
        __syncthreads();
        s = red[0] + red[1];
        Qzh[(size_t)row * Dn + t] = (f16)(e / s);
    }
}

extern "C" void kernel_launch(void* const* d_in, const int* in_sizes, int n_in,
                              void* d_out, int out_size, void* d_ws, size_t ws_size,
                              hipStream_t stream) {
    const float* x       = (const float*)d_in[0];
    const int*   mask    = (const int*)d_in[1];
    const float* ternary = (const float*)d_in[2];
    const float* global_ = (const float*)d_in[3];
    float* out = (float*)d_out;
    (void)ws_size; (void)n_in; (void)in_sizes; (void)out_size;

    char* ws = (char*)d_ws;
    size_t o = 0;
    f16* Qzh = (f16*)(ws + o); o += (size_t)Bn * Ln * Dn * 2;
    f16* U   = (f16*)(ws + o); o += (size_t)Bn * Hn * Ln * Dn * 2;
    f16* Ut  = (f16*)(ws + o); o += (size_t)Bn * Hn * Ln * Dn * 2;
    f16* Vt  = (f16*)(ws + o); o += (size_t)Bn * Hn * Ln * Dn * 2;
    f16* TpA = (f16*)(ws + o); o += (size_t)Hn * Dn * Dn * 2;
    f16* TpB = (f16*)(ws + o); o += (size_t)Hn * Dn * Dn * 2;
    f16* GpA = (f16*)(ws + o); o += (size_t)Hn * Gn * Dn * 2;
    f16* Gpt = (f16*)(ws + o); o += (size_t)Hn * Dn * Gn * 2;
    float* rowLp = (float*)(ws + o); o += (size_t)2 * Bn * Hn * Ln * 4;
    f16* Mi  = (f16*)(ws + o); o += (size_t)2 * Bn * Hn * Ln * Dn * 2;
    f16* Mj  = (f16*)(ws + o); o += (size_t)2 * Bn * Hn * Ln * Dn * 2;

    repack_kernel<<<(Dn * Dn * Hn + 255) / 256, 256, 0, stream>>>(ternary, global_, TpA, TpB, GpA, Gpt);
    softmax_rows_kernel<<<Bn * Ln, 128, 0, stream>>>(x, Qzh);

    for (int it = 0; it < NITERS; it++) {
        uv_kernel<<<dim3(Ln / 64, Hn, Bn), 256, 0, stream>>>(Qzh, TpA, TpB, mask, U, Ut, Vt);
        msgi_kernel<<<dim3(Ln / 128 * 2 * Hn * Bn), 512, 0, stream>>>(Qzh, U, Ut, GpA, Gpt, Mi, rowLp);
        msgj_kernel<<<dim3(Ln / 128 * 2 * Hn * Bn), 512, 0, stream>>>(Qzh, U, Vt, mask, rowLp, Mj);
        combine_kernel<<<Bn * Ln, 128, 0, stream>>>(x, Mi, Mj, rowLp, mask, out, Qzh,
                                                    (it < NITERS - 1) ? 1 : 0,
                                                    (it == NITERS - 1) ? 1 : 0);
    }
}

// Round 11
// 353.028 us; speedup vs baseline: 1.2992x; 1.2992x over previous
//
#include <hip/hip_runtime.h>
#include <math.h>

#define Bn 4
#define Ln 1024
#define Dn 128
#define Hn 8
#define Gn 64
#define NITERS 4

typedef _Float16 f16;
typedef _Float16 half8 __attribute__((ext_vector_type(8)));
typedef _Float16 half4v __attribute__((ext_vector_type(4)));
typedef float floatx4 __attribute__((ext_vector_type(4)));

#define WPAD 136   // f16 stride for uv_kernel row-major tiles

#define MFMA(a, b, c) __builtin_amdgcn_mfma_f32_16x16x32_f16((a), (b), (c), 0, 0, 0)

union h8u { half8 h; half4v v[2]; };

// async global->LDS, 16B per lane; dest = lds_base + lane*16 (wave-uniform base)
__device__ __forceinline__ void gl_lds16(const f16* g, f16* l) {
    __builtin_amdgcn_global_load_lds(
        (const __attribute__((address_space(1))) void*)(g),
        (__attribute__((address_space(3))) void*)(l),
        16, 0, 0);
}

// 8-wave version: issue one 64x128 tile (row stride Dn) into UsB and one
// 128x64 tile (row stride sb) into UbB, XOR-swizzled (16B-group g stored at
// g^(row&7)). Each wave: 2 chunks of each tile (2KB + 2KB).
__device__ __forceinline__ void issue_tiles8(const f16* us, const f16* ub, int sb,
                                             f16* UsB, f16* UbB, int w, int l) {
    #pragma unroll
    for (int k = 0; k < 2; k++) {
        int c = w * 2 + k;
        {   // Us: 64 rows x 16 groups
            int r = c * 4 + (l >> 4); int g = (l & 15) ^ (r & 7);
            gl_lds16(us + (size_t)r * Dn + g * 8, UsB + c * 512);
        }
        {   // Ub: 128 rows x 8 groups
            int r = c * 8 + (l >> 3); int g = (l & 7) ^ (r & 7);
            gl_lds16(ub + (size_t)r * sb + g * 8, UbB + c * 512);
        }
    }
}

// ---------------- repack ternary/global into f16 per-head layouts -----------
// Gpt columns are pre-permuted by pi (see msgi PV k-ordering):
// pos(g) = (g>>5)*32 + ((g>>2)&3)*8 + ((g>>4)&1)*4 + (g&3)
__global__ void repack_kernel(const float* __restrict__ ter, const float* __restrict__ glb,
                              f16* __restrict__ TpA, f16* __restrict__ TpB,
                              f16* __restrict__ GpA, f16* __restrict__ Gpt) {
    int idx = blockIdx.x * 256 + threadIdx.x;
    if (idx < Dn * Dn * Hn) {
        int h = idx % Hn; int b = (idx / Hn) % Dn; int a = idx / (Hn * Dn);
        f16 v = (f16)ter[idx];
        TpA[((size_t)h * Dn + a) * Dn + b] = v;
        TpB[((size_t)h * Dn + b) * Dn + a] = v;
    }
    if (idx < Gn * Dn * Hn) {
        int h = idx % Hn; int a = (idx / Hn) % Dn; int g = idx / (Hn * Dn);
        f16 v = (f16)glb[idx];
        GpA[((size_t)h * Gn + g) * Dn + a] = v;
        int pos = ((g >> 5) << 5) | (((g >> 2) & 3) << 3) | (((g >> 4) & 1) << 2) | (g & 3);
        Gpt[((size_t)h * Dn + a) * Gn + pos] = v;
    }
}

// ---------------- row softmax over D=128 (fp32 in, f16 out) -----------------
__global__ void softmax_rows_kernel(const float* __restrict__ in, f16* __restrict__ out) {
    int row = blockIdx.x;
    int t = threadIdx.x;  // 0..127
    __shared__ float red[2];
    float v = in[(size_t)row * Dn + t];
    float m = v;
    #pragma unroll
    for (int off = 1; off < 64; off <<= 1) m = fmaxf(m, __shfl_xor(m, off, 64));
    if ((t & 63) == 0) red[t >> 6] = m;
    __syncthreads();
    m = fmaxf(red[0], red[1]);
    float e = __expf(v - m);
    float s = e;
    #pragma unroll
    for (int off = 1; off < 64; off <<= 1) s += __shfl_xor(s, off, 64);
    __syncthreads();
    if ((t & 63) == 0) red[t >> 6] = s;
    __syncthreads();
    s = red[0] + red[1];
    out[(size_t)row * Dn + t] = (f16)(e / s);
}

// ---------------- U/V projection via MFMA ----------------------------------
// Ut/Vt columns stored pi-permuted within each 64-tile:
// pos = (w>>1)*32 + q*8 + (w&1)*4 (+reg), matching msgi/msgj PV B-reads.
// U/Ut carry a -64 bias on masked-j rows: Qz rows sum to 1, so scores vs
// masked j shift by -64 -> exp ~= 0 (replaces j-mask checks in msgi+msgj).
__launch_bounds__(256, 4)
__global__ void uv_kernel(const f16* __restrict__ Qz, const f16* __restrict__ TpA,
                          const f16* __restrict__ TpB, const int* __restrict__ mask,
                          f16* __restrict__ U, f16* __restrict__ Ut, f16* __restrict__ Vt) {
    int bx = blockIdx.x;  // 16 j-strips of 64
    int h  = blockIdx.y;
    int n  = blockIdx.z;
    int t  = threadIdx.x;
    int w = t >> 6, l = t & 63, m = l & 15, q = l >> 4;

    __shared__ __align__(16) f16 Ts[128 * WPAD];

    int jrow = bx * 64 + w * 16 + m;
    const f16* qbase = Qz + ((size_t)n * Ln + jrow) * Dn;
    half8 aq[4];
    #pragma unroll
    for (int ks = 0; ks < 4; ks++)
        aq[ks] = *(const half8*)(qbase + ks * 32 + q * 8);

    size_t hoff = (size_t)(n * Hn + h);
    int jr0 = bx * 64 + w * 16 + 4 * q;
    int jrp = bx * 64 + (w >> 1) * 32 + q * 8 + (w & 1) * 4;  // pi^-1 position

    float bias[4];
    #pragma unroll
    for (int reg = 0; reg < 4; reg++)
        bias[reg] = mask[n * Ln + jr0 + reg] ? 0.f : -64.f;

    // ---- pass 1: U = Qz * TpA^T (biased) ----
    {
        const f16* src = TpA + (size_t)h * Dn * Dn;
        for (int ii = 0; ii < 8; ii++) {
            int idx = t + 256 * ii; int r = idx >> 4, c = idx & 15;
            *(float4*)&Ts[r * WPAD + c * 8] = *(const float4*)(src + (size_t)r * Dn + c * 8);
        }
        __syncthreads();
        #pragma unroll
        for (int ct = 0; ct < 8; ct++) {
            floatx4 acc = {0.f, 0.f, 0.f, 0.f};
            #pragma unroll
            for (int ks = 0; ks < 4; ks++) {
                half8 b = *(const half8*)&Ts[(ct * 16 + m) * WPAD + ks * 32 + q * 8];
                acc = MFMA(aq[ks], b, acc);
            }
            f16* ub = U + (hoff * Ln + jr0) * Dn + ct * 16 + m;
            half4v pk;
            #pragma unroll
            for (int reg = 0; reg < 4; reg++) {
                f16 v = (f16)(acc[reg] + bias[reg]);
                ub[(size_t)reg * Dn] = v;
                pk[reg] = v;
            }
            *(half4v*)(Ut + (hoff * Dn + ct * 16 + m) * Ln + jrp) = pk;
        }
        __syncthreads();
    }
    // ---- pass 2: V = Qz * TpB^T, stored transposed (pi-permuted, unbiased) --
    {
        const f16* src = TpB + (size_t)h * Dn * Dn;
        for (int ii = 0; ii < 8; ii++) {
            int idx = t + 256 * ii; int r = idx >> 4, c = idx & 15;
            *(float4*)&Ts[r * WPAD + c * 8] = *(const float4*)(src + (size_t)r * Dn + c * 8);
        }
        __syncthreads();
        #pragma unroll
        for (int ct = 0; ct < 8; ct++) {
            floatx4 acc = {0.f, 0.f, 0.f, 0.f};
            #pragma unroll
            for (int ks = 0; ks < 4; ks++) {
                half8 b = *(const half8*)&Ts[(ct * 16 + m) * WPAD + ks * 32 + q * 8];
                acc = MFMA(aq[ks], b, acc);
            }
            half4v pk = { (f16)acc[0], (f16)acc[1], (f16)acc[2], (f16)acc[3] };
            *(half4v*)(Vt + (hoff * Dn + ct * 16 + m) * Ln + jrp) = pk;
        }
    }
}

// ---------------- msg_i + msg_g: 8-wave, register-resident P, 1 barrier -----
// Exact R6 structure (verified 372.3us) with: (1) j-mask folded into U's -64
// bias -> jms array, its LDS reads, and 8 selects/wave/jt removed; exp is
// branch-free (G-tile needs no special case). (2) setprio around PV MFMA.
__launch_bounds__(512, 2)
__global__ void msgi_kernel(const f16* __restrict__ Qz, const f16* __restrict__ U,
                            const f16* __restrict__ Ut, const f16* __restrict__ GpA,
                            const f16* __restrict__ Gpt, const int* __restrict__ mask,
                            f16* __restrict__ Macc, float* __restrict__ rowLinv) {
    int p = blockIdx.x;              // dispatch order; XCD = p % 8 owns head h
    int h  = p & 7;
    int it = (p >> 3) & 15;
    int n  = p >> 7;
    int t = threadIdx.x;
    int w = t >> 6, l = t & 63, m = l & 15, q = l >> 4;
    int ihw = w >> 1;  // i-row quarter (16 rows)
    int kw  = w & 1;   // j-half of the reduction

    __shared__ __align__(16) f16 Us[2][64 * 128];    // U j-tile, swizzled
    __shared__ __align__(16) f16 Ub[2][128 * 64];    // Ut slice [a][j'], swizzled
    __shared__ float lredS[4][2][16];
    __shared__ float linvS[64];

    // resident B-frags: Qz rows of this wave's 16 i (jt-invariant)
    half8 bq[4];
    {
        const f16* qr = Qz + ((size_t)n * Ln + it * 64 + ihw * 16 + m) * Dn;
        #pragma unroll
        for (int ks = 0; ks < 4; ks++)
            bq[ks] = *(const half8*)(qr + ks * 32 + q * 8);
    }

    float lacc = 0.f;
    floatx4 Oacc[8];
    #pragma unroll
    for (int at = 0; at < 8; at++) Oacc[at] = (floatx4){0.f, 0.f, 0.f, 0.f};

    size_t hoff = (size_t)(n * Hn + h);

    // preload jt=0
    issue_tiles8(U + hoff * Ln * Dn, Ut + hoff * Dn * Ln, Ln, Us[0], Ub[0], w, l);
    __syncthreads();

    for (int jt = 0; jt < 17; jt++) {
        int cur = jt & 1, nxt = cur ^ 1;
        if (jt + 1 < 17) {
            const f16 *us, *ub; int sb;
            if (jt + 1 < 16) {
                us = U + (hoff * Ln + (size_t)(jt + 1) * 64) * Dn;
                ub = Ut + hoff * Dn * Ln + (jt + 1) * 64;
                sb = Ln;
            } else {
                us = GpA + (size_t)h * Gn * Dn;
                ub = Gpt + (size_t)h * Dn * Gn;
                sb = Gn;
            }
            issue_tiles8(us, ub, sb, Us[nxt], Ub[nxt], w, l);
        }
        // scores S^T[j][i] for jb = 2kw+jb2, this wave's 16 i (mask in bias)
        half4v hv[2];
        #pragma unroll
        for (int jb2 = 0; jb2 < 2; jb2++) {
            int jb = kw * 2 + jb2;
            int r0 = jb * 16 + m;
            half8 au[4];
            #pragma unroll
            for (int ks = 0; ks < 4; ks++)
                au[ks] = *(const half8*)&Us[cur][((size_t)r0 << 7) + ((((ks << 2) + q)) ^ (r0 & 7)) * 8];
            floatx4 s = {0.f, 0.f, 0.f, 0.f};
            #pragma unroll
            for (int ks = 0; ks < 4; ks++) s = MFMA(au[ks], bq[ks], s);
            half4v pk;
            #pragma unroll
            for (int reg = 0; reg < 4; reg++) {
                float p2 = __expf(fminf(s[reg], 11.f));   // masked j -> s-64 -> ~0
                lacc += p2;
                pk[reg] = (f16)p2;
            }
            hv[jb2] = pk;
        }

        // PV (kst = kw): O[i][a] += P[i][j] * U[j][a]; A = own packed scores
        // (pi k-order), B from pi-permuted swizzled Ub[cur].
        {
            h8u u; u.v[0] = hv[0]; u.v[1] = hv[1];
            half8 aP = u.h;
            __builtin_amdgcn_s_setprio(1);
            #pragma unroll
            for (int at = 0; at < 8; at++) {
                int r0 = at * 16 + m;
                half8 bU = *(const half8*)&Ub[cur][((size_t)r0 << 6) + ((((kw << 2) + q)) ^ (r0 & 7)) * 8];
                Oacc[at] = MFMA(aP, bU, Oacc[at]);
            }
            __builtin_amdgcn_s_setprio(0);
        }
        __syncthreads();  // single barrier: drains jt+1 DMA, releases cur
    }

    // ---- epilogue ----
    lacc += __shfl_xor(lacc, 16, 64);
    lacc += __shfl_xor(lacc, 32, 64);
    if (q == 0) lredS[ihw][kw][m] = lacc;
    __syncthreads();
    size_t rbase = hoff * Ln + (size_t)it * 64;
    float* ox = (float*)Us;  // [4][64][32] floats = 32KB
    if (t < 64) {
        float inv = 1.0f / (lredS[t >> 4][0][t & 15] + lredS[t >> 4][1][t & 15]);
        linvS[t] = inv;
        int mk = mask[n * Ln + it * 64 + t];
        rowLinv[rbase + t] = mk ? inv : 0.f;  // i-mask folded for msgj
    }
    if (kw == 1) {
        float* od = ox + ((size_t)ihw * 64 + l) * 32;
        #pragma unroll
        for (int at = 0; at < 8; at++)
            *(floatx4*)(od + at * 4) = Oacc[at];
    }
    __syncthreads();
    if (kw == 0) {
        const float* od = ox + ((size_t)ihw * 64 + l) * 32;
        f16* Mo = Macc + rbase * Dn;
        #pragma unroll
        for (int reg = 0; reg < 4; reg++) {
            int row = ihw * 16 + 4 * q + reg;
            float inv = linvS[row];
            #pragma unroll
            for (int at = 0; at < 8; at++) {
                float v = Oacc[at][reg] + od[at * 4 + reg];
                Mo[(size_t)row * Dn + at * 16 + m] = (f16)(v * inv);
            }
        }
    }
}

// ---------------- msg_j: mirrored 8-wave, register-resident P' --------------
__launch_bounds__(512, 2)
__global__ void msgj_kernel(const f16* __restrict__ Qz, const f16* __restrict__ U,
                            const f16* __restrict__ Vt, const int* __restrict__ mask,
                            const float* __restrict__ rowLinv, f16* __restrict__ Macc) {
    int p = blockIdx.x;              // dispatch order; XCD = p % 8 owns head h
    int h  = p & 7;
    int jt = (p >> 3) & 15;
    int n  = p >> 7;
    int t = threadIdx.x;
    int w = t >> 6, l = t & 63, m = l & 15, q = l >> 4;
    int jhw = w >> 1;  // j-row quarter (16 rows)
    int kw  = w & 1;   // i-half of the reduction

    __shared__ __align__(16) f16 Qs[2][64 * 128];   // Qz i-tile, swizzled
    __shared__ __align__(16) f16 Vb[2][128 * 64];   // Vt slice [b][i'], swizzled
    __shared__ __align__(16) float lvS[2][64];

    size_t hoff = (size_t)(n * Hn + h);

    // resident B-frags: U rows of this wave's 16 j (bias carries j-mask)
    half8 bu[4];
    {
        const f16* ur = U + (hoff * Ln + (size_t)jt * 64 + jhw * 16 + m) * Dn;
        #pragma unroll
        for (int ks = 0; ks < 4; ks++)
            bu[ks] = *(const half8*)(ur + ks * 32 + q * 8);
    }

    floatx4 Oacc[8];
    #pragma unroll
    for (int bt = 0; bt < 8; bt++) Oacc[bt] = (floatx4){0.f, 0.f, 0.f, 0.f};

    // preload it2=0
    issue_tiles8(Qz + (size_t)n * Ln * Dn, Vt + hoff * Dn * Ln, Ln, Qs[0], Vb[0], w, l);
    if (t < 64) lvS[0][t] = rowLinv[hoff * Ln + t];
    __syncthreads();

    for (int it2 = 0; it2 < 16; it2++) {
        int cur = it2 & 1, nxt = cur ^ 1;
        if (it2 + 1 < 16) {
            issue_tiles8(Qz + ((size_t)n * Ln + (size_t)(it2 + 1) * 64) * Dn,
                         Vt + hoff * Dn * Ln + (it2 + 1) * 64, Ln, Qs[nxt], Vb[nxt], w, l);
            if (t < 64) lvS[nxt][t] = rowLinv[hoff * Ln + (it2 + 1) * 64 + t];
        }
        // scores S[i][j] for ibt = 2kw+ib2, this wave's 16 j (mask in bu bias)
        half4v hv[2];
        #pragma unroll
        for (int ib2 = 0; ib2 < 2; ib2++) {
            int ibt = kw * 2 + ib2;
            int r0 = ibt * 16 + m;
            half8 aq2[4];
            #pragma unroll
            for (int ks = 0; ks < 4; ks++)
                aq2[ks] = *(const half8*)&Qs[cur][((size_t)r0 << 7) + ((((ks << 2) + q)) ^ (r0 & 7)) * 8];
            float4 lv = *(const float4*)&lvS[cur][ibt * 16 + 4 * q];
            float lv4[4] = { lv.x, lv.y, lv.z, lv.w };
            floatx4 s = {0.f, 0.f, 0.f, 0.f};
            #pragma unroll
            for (int ks = 0; ks < 4; ks++) s = MFMA(aq2[ks], bu[ks], s);
            half4v pk;
            #pragma unroll
            for (int reg = 0; reg < 4; reg++)
                pk[reg] = (f16)(__expf(fminf(s[reg], 11.f)) * lv4[reg]);
            hv[ib2] = pk;
        }

        // PV (kst = kw): O[j][b] += P'[j][i] * V[i][b]
        {
            h8u u; u.v[0] = hv[0]; u.v[1] = hv[1];
            half8 aP = u.h;
            __builtin_amdgcn_s_setprio(1);
            #pragma unroll
            for (int bt = 0; bt < 8; bt++) {
                int r0 = bt * 16 + m;
                half8 bV = *(const half8*)&Vb[cur][((size_t)r0 << 6) + ((((kw << 2) + q)) ^ (r0 & 7)) * 8];
                Oacc[bt] = MFMA(aP, bV, Oacc[bt]);
            }
            __builtin_amdgcn_s_setprio(0);
        }
        __syncthreads();  // single barrier per it2
    }

    // ---- epilogue: pair-reduce Oacc across kw, then RMW Macc ----
    float* ox = (float*)Qs;  // reuse, [4][64][32] floats
    if (kw == 1) {
        float* od = ox + ((size_t)jhw * 64 + l) * 32;
        #pragma unroll
        for (int bt = 0; bt < 8; bt++)
            *(floatx4*)(od + bt * 4) = Oacc[bt];
    }
    __syncthreads();
    if (kw == 0) {
        const float* od = ox + ((size_t)jhw * 64 + l) * 32;
        f16* Mo = Macc + (hoff * Ln + (size_t)jt * 64) * Dn;
        #pragma unroll
        for (int reg = 0; reg < 4; reg++) {
            int row = jhw * 16 + 4 * q + reg;
            #pragma unroll
            for (int bt = 0; bt < 8; bt++) {
                f16* p2 = &Mo[(size_t)row * Dn + bt * 16 + m];
                float v = Oacc[bt][reg] + od[bt * 4 + reg];
                *p2 = (f16)((float)*p2 + v);
            }
        }
    }
}

// ---------------- fused combine (+softmax | +mask) --------------------------
__global__ void combine_kernel(const float* __restrict__ x, const f16* __restrict__ Macc,
                               const int* __restrict__ mask, float* __restrict__ out,
                               f16* __restrict__ Qzh, int do_softmax, int do_mask) {
    int row = blockIdx.x;           // B*L rows
    int t = threadIdx.x;            // 0..127
    __shared__ float red[2];
    int n = row >> 10;
    float acc = x[(size_t)row * Dn + t];
    const f16* mp = Macc + (size_t)n * Hn * Ln * Dn + (size_t)(row & 1023) * Dn + t;
    #pragma unroll
    for (int h = 0; h < Hn; h++) acc += (float)mp[(size_t)h * Ln * Dn];
    float o = acc;
    if (do_mask && mask[row] == 0) o = 0.f;
    out[(size_t)row * Dn + t] = o;
    if (do_softmax) {
        float m = acc;
        #pragma unroll
        for (int off = 1; off < 64; off <<= 1) m = fmaxf(m, __shfl_xor(m, off, 64));
        if ((t & 63) == 0) red[t >> 6] = m;
        __syncthreads();
        m = fmaxf(red[0], red[1]);
        float e = __expf(acc - m);
        float s = e;
        #pragma unroll
        for (int off = 1; off < 64; off <<= 1) s += __shfl_xor(s, off, 64);
        __syncthreads();
        if ((t & 63) == 0) red[t >> 6] = s;
        __syncthreads();
        s = red[0] + red[1];
        Qzh[(size_t)row * Dn + t] = (f16)(e / s);
    }
}

extern "C" void kernel_launch(void* const* d_in, const int* in_sizes, int n_in,
                              void* d_out, int out_size, void* d_ws, size_t ws_size,
                              hipStream_t stream) {
    const float* x       = (const float*)d_in[0];
    const int*   mask    = (const int*)d_in[1];
    const float* ternary = (const float*)d_in[2];
    const float* global_ = (const float*)d_in[3];
    float* out = (float*)d_out;
    (void)ws_size; (void)n_in; (void)in_sizes; (void)out_size;

    char* ws = (char*)d_ws;
    size_t o = 0;
    f16* Qzh = (f16*)(ws + o); o += (size_t)Bn * Ln * Dn * 2;
    f16* U   = (f16*)(ws + o); o += (size_t)Bn * Hn * Ln * Dn * 2;
    f16* Ut  = (f16*)(ws + o); o += (size_t)Bn * Hn * Ln * Dn * 2;
    f16* Vt  = (f16*)(ws + o); o += (size_t)Bn * Hn * Ln * Dn * 2;
    f16* TpA = (f16*)(ws + o); o += (size_t)Hn * Dn * Dn * 2;
    f16* TpB = (f16*)(ws + o); o += (size_t)Hn * Dn * Dn * 2;
    f16* GpA = (f16*)(ws + o); o += (size_t)Hn * Gn * Dn * 2;
    f16* Gpt = (f16*)(ws + o); o += (size_t)Hn * Dn * Gn * 2;
    float* rowLinv = (float*)(ws + o); o += (size_t)Bn * Hn * Ln * 4;
    f16* Macc = (f16*)(ws + o); o += (size_t)Bn * Hn * Ln * Dn * 2;

    repack_kernel<<<(Dn * Dn * Hn + 255) / 256, 256, 0, stream>>>(ternary, global_, TpA, TpB, GpA, Gpt);
    softmax_rows_kernel<<<Bn * Ln, 128, 0, stream>>>(x, Qzh);

    for (int it = 0; it < NITERS; it++) {
        uv_kernel<<<dim3(Ln / 64, Hn, Bn), 256, 0, stream>>>(Qzh, TpA, TpB, mask, U, Ut, Vt);
        msgi_kernel<<<dim3(Ln / 64 * Hn * Bn), 512, 0, stream>>>(Qzh, U, Ut, GpA, Gpt, mask, Macc, rowLinv);
        msgj_kernel<<<dim3(Ln / 64 * Hn * Bn), 512, 0, stream>>>(Qzh, U, Vt, mask, rowLinv, Macc);
        combine_kernel<<<Bn * Ln, 128, 0, stream>>>(x, Macc, mask, out, Qzh,
                                                    (it < NITERS - 1) ? 1 : 0,
                                                    (it == NITERS - 1) ? 1 : 0);
    }
}

// Round 12
// 346.558 us; speedup vs baseline: 1.3234x; 1.0187x over previous
//
#include <hip/hip_runtime.h>
#include <math.h>

#define Bn 4
#define Ln 1024
#define Dn 128
#define Hn 8
#define Gn 64
#define NITERS 4

typedef _Float16 f16;
typedef _Float16 half8 __attribute__((ext_vector_type(8)));
typedef _Float16 half4v __attribute__((ext_vector_type(4)));
typedef float floatx4 __attribute__((ext_vector_type(4)));

#define WPAD 136   // f16 stride for uv_kernel row-major tiles

#define MFMA(a, b, c) __builtin_amdgcn_mfma_f32_16x16x32_f16((a), (b), (c), 0, 0, 0)

union h8u { half8 h; half4v v[2]; };

// async global->LDS, 16B per lane; dest = lds_base + lane*16 (wave-uniform base)
__device__ __forceinline__ void gl_lds16(const f16* g, f16* l) {
    __builtin_amdgcn_global_load_lds(
        (const __attribute__((address_space(1))) void*)(g),
        (__attribute__((address_space(3))) void*)(l),
        16, 0, 0);
}

// 8-wave version: issue one 64x128 tile (row stride Dn) into UsB and one
// 128x64 tile (row stride sb) into UbB, XOR-swizzled (16B-group g stored at
// g^(row&7)). Each wave: 2 chunks of each tile (2KB + 2KB).
__device__ __forceinline__ void issue_tiles8(const f16* us, const f16* ub, int sb,
                                             f16* UsB, f16* UbB, int w, int l) {
    #pragma unroll
    for (int k = 0; k < 2; k++) {
        int c = w * 2 + k;
        {   // Us: 64 rows x 16 groups
            int r = c * 4 + (l >> 4); int g = (l & 15) ^ (r & 7);
            gl_lds16(us + (size_t)r * Dn + g * 8, UsB + c * 512);
        }
        {   // Ub: 128 rows x 8 groups
            int r = c * 8 + (l >> 3); int g = (l & 7) ^ (r & 7);
            gl_lds16(ub + (size_t)r * sb + g * 8, UbB + c * 512);
        }
    }
}

// ---------------- repack ternary/global into f16 per-head layouts -----------
// Gpt columns are pre-permuted by pi (see msgi PV k-ordering):
// pos(g) = (g>>5)*32 + ((g>>2)&3)*8 + ((g>>4)&1)*4 + (g&3)
__global__ void repack_kernel(const float* __restrict__ ter, const float* __restrict__ glb,
                              f16* __restrict__ TpA, f16* __restrict__ TpB,
                              f16* __restrict__ GpA, f16* __restrict__ Gpt) {
    int idx = blockIdx.x * 256 + threadIdx.x;
    if (idx < Dn * Dn * Hn) {
        int h = idx % Hn; int b = (idx / Hn) % Dn; int a = idx / (Hn * Dn);
        f16 v = (f16)ter[idx];
        TpA[((size_t)h * Dn + a) * Dn + b] = v;
        TpB[((size_t)h * Dn + b) * Dn + a] = v;
    }
    if (idx < Gn * Dn * Hn) {
        int h = idx % Hn; int a = (idx / Hn) % Dn; int g = idx / (Hn * Dn);
        f16 v = (f16)glb[idx];
        GpA[((size_t)h * Gn + g) * Dn + a] = v;
        int pos = ((g >> 5) << 5) | (((g >> 2) & 3) << 3) | (((g >> 4) & 1) << 2) | (g & 3);
        Gpt[((size_t)h * Dn + a) * Gn + pos] = v;
    }
}

// ---------------- row softmax over D=128 (fp32 in, f16 out) -----------------
__global__ void softmax_rows_kernel(const float* __restrict__ in, f16* __restrict__ out) {
    int row = blockIdx.x;
    int t = threadIdx.x;  // 0..127
    __shared__ float red[2];
    float v = in[(size_t)row * Dn + t];
    float m = v;
    #pragma unroll
    for (int off = 1; off < 64; off <<= 1) m = fmaxf(m, __shfl_xor(m, off, 64));
    if ((t & 63) == 0) red[t >> 6] = m;
    __syncthreads();
    m = fmaxf(red[0], red[1]);
    float e = __expf(v - m);
    float s = e;
    #pragma unroll
    for (int off = 1; off < 64; off <<= 1) s += __shfl_xor(s, off, 64);
    __syncthreads();
    if ((t & 63) == 0) red[t >> 6] = s;
    __syncthreads();
    s = red[0] + red[1];
    out[(size_t)row * Dn + t] = (f16)(e / s);
}

// ---------------- U/V projection via MFMA ----------------------------------
// Ut/Vt columns stored pi-permuted within each 64-tile:
// pos = (w>>1)*32 + q*8 + (w&1)*4 (+reg), matching msgi/msgj PV B-reads.
// U/Ut carry a -64 bias on masked-j rows: Qz rows sum to 1, so scores vs
// masked j shift by -64 -> exp ~= 0 (replaces j-mask checks in msgi+msgj).
// 1-D grid, h = p&7: the XCD writing U/Ut/Vt for (n,h) is the SAME XCD that
// msgi/msgj read them from -> producer-consumer L2 locality.
__launch_bounds__(256, 4)
__global__ void uv_kernel(const f16* __restrict__ Qz, const f16* __restrict__ TpA,
                          const f16* __restrict__ TpB, const int* __restrict__ mask,
                          f16* __restrict__ U, f16* __restrict__ Ut, f16* __restrict__ Vt) {
    int p  = blockIdx.x;             // XCD = p % 8 owns head h
    int h  = p & 7;
    int bx = (p >> 3) & 15;          // 16 j-strips of 64
    int n  = p >> 7;
    int t  = threadIdx.x;
    int w = t >> 6, l = t & 63, m = l & 15, q = l >> 4;

    __shared__ __align__(16) f16 Ts[128 * WPAD];

    int jrow = bx * 64 + w * 16 + m;
    const f16* qbase = Qz + ((size_t)n * Ln + jrow) * Dn;
    half8 aq[4];
    #pragma unroll
    for (int ks = 0; ks < 4; ks++)
        aq[ks] = *(const half8*)(qbase + ks * 32 + q * 8);

    size_t hoff = (size_t)(n * Hn + h);
    int jr0 = bx * 64 + w * 16 + 4 * q;
    int jrp = bx * 64 + (w >> 1) * 32 + q * 8 + (w & 1) * 4;  // pi^-1 position

    float bias[4];
    #pragma unroll
    for (int reg = 0; reg < 4; reg++)
        bias[reg] = mask[n * Ln + jr0 + reg] ? 0.f : -64.f;

    // ---- pass 1: U = Qz * TpA^T (biased) ----
    {
        const f16* src = TpA + (size_t)h * Dn * Dn;
        for (int ii = 0; ii < 8; ii++) {
            int idx = t + 256 * ii; int r = idx >> 4, c = idx & 15;
            *(float4*)&Ts[r * WPAD + c * 8] = *(const float4*)(src + (size_t)r * Dn + c * 8);
        }
        __syncthreads();
        #pragma unroll
        for (int ct = 0; ct < 8; ct++) {
            floatx4 acc = {0.f, 0.f, 0.f, 0.f};
            #pragma unroll
            for (int ks = 0; ks < 4; ks++) {
                half8 b = *(const half8*)&Ts[(ct * 16 + m) * WPAD + ks * 32 + q * 8];
                acc = MFMA(aq[ks], b, acc);
            }
            f16* ub = U + (hoff * Ln + jr0) * Dn + ct * 16 + m;
            half4v pk;
            #pragma unroll
            for (int reg = 0; reg < 4; reg++) {
                f16 v = (f16)(acc[reg] + bias[reg]);
                ub[(size_t)reg * Dn] = v;
                pk[reg] = v;
            }
            *(half4v*)(Ut + (hoff * Dn + ct * 16 + m) * Ln + jrp) = pk;
        }
        __syncthreads();
    }
    // ---- pass 2: V = Qz * TpB^T, stored transposed (pi-permuted, unbiased) --
    {
        const f16* src = TpB + (size_t)h * Dn * Dn;
        for (int ii = 0; ii < 8; ii++) {
            int idx = t + 256 * ii; int r = idx >> 4, c = idx & 15;
            *(float4*)&Ts[r * WPAD + c * 8] = *(const float4*)(src + (size_t)r * Dn + c * 8);
        }
        __syncthreads();
        #pragma unroll
        for (int ct = 0; ct < 8; ct++) {
            floatx4 acc = {0.f, 0.f, 0.f, 0.f};
            #pragma unroll
            for (int ks = 0; ks < 4; ks++) {
                half8 b = *(const half8*)&Ts[(ct * 16 + m) * WPAD + ks * 32 + q * 8];
                acc = MFMA(aq[ks], b, acc);
            }
            half4v pk = { (f16)acc[0], (f16)acc[1], (f16)acc[2], (f16)acc[3] };
            *(half4v*)(Vt + (hoff * Dn + ct * 16 + m) * Ln + jrp) = pk;
        }
    }
}

// ---------------- msg_i + msg_g: 8-wave, register-resident P, 1 barrier -----
// R11 structure (verified 353.0us): j-mask folded into U's -64 bias; setprio
// now wraps BOTH MFMA clusters (scores + PV).
__launch_bounds__(512, 2)
__global__ void msgi_kernel(const f16* __restrict__ Qz, const f16* __restrict__ U,
                            const f16* __restrict__ Ut, const f16* __restrict__ GpA,
                            const f16* __restrict__ Gpt, const int* __restrict__ mask,
                            f16* __restrict__ Macc, float* __restrict__ rowLinv) {
    int p = blockIdx.x;              // dispatch order; XCD = p % 8 owns head h
    int h  = p & 7;
    int it = (p >> 3) & 15;
    int n  = p >> 7;
    int t = threadIdx.x;
    int w = t >> 6, l = t & 63, m = l & 15, q = l >> 4;
    int ihw = w >> 1;  // i-row quarter (16 rows)
    int kw  = w & 1;   // j-half of the reduction

    __shared__ __align__(16) f16 Us[2][64 * 128];    // U j-tile, swizzled
    __shared__ __align__(16) f16 Ub[2][128 * 64];    // Ut slice [a][j'], swizzled
    __shared__ float lredS[4][2][16];
    __shared__ float linvS[64];

    // resident B-frags: Qz rows of this wave's 16 i (jt-invariant)
    half8 bq[4];
    {
        const f16* qr = Qz + ((size_t)n * Ln + it * 64 + ihw * 16 + m) * Dn;
        #pragma unroll
        for (int ks = 0; ks < 4; ks++)
            bq[ks] = *(const half8*)(qr + ks * 32 + q * 8);
    }

    float lacc = 0.f;
    floatx4 Oacc[8];
    #pragma unroll
    for (int at = 0; at < 8; at++) Oacc[at] = (floatx4){0.f, 0.f, 0.f, 0.f};

    size_t hoff = (size_t)(n * Hn + h);

    // preload jt=0
    issue_tiles8(U + hoff * Ln * Dn, Ut + hoff * Dn * Ln, Ln, Us[0], Ub[0], w, l);
    __syncthreads();

    for (int jt = 0; jt < 17; jt++) {
        int cur = jt & 1, nxt = cur ^ 1;
        if (jt + 1 < 17) {
            const f16 *us, *ub; int sb;
            if (jt + 1 < 16) {
                us = U + (hoff * Ln + (size_t)(jt + 1) * 64) * Dn;
                ub = Ut + hoff * Dn * Ln + (jt + 1) * 64;
                sb = Ln;
            } else {
                us = GpA + (size_t)h * Gn * Dn;
                ub = Gpt + (size_t)h * Dn * Gn;
                sb = Gn;
            }
            issue_tiles8(us, ub, sb, Us[nxt], Ub[nxt], w, l);
        }
        // scores S^T[j][i] for jb = 2kw+jb2, this wave's 16 i (mask in bias)
        half4v hv[2];
        #pragma unroll
        for (int jb2 = 0; jb2 < 2; jb2++) {
            int jb = kw * 2 + jb2;
            int r0 = jb * 16 + m;
            half8 au[4];
            #pragma unroll
            for (int ks = 0; ks < 4; ks++)
                au[ks] = *(const half8*)&Us[cur][((size_t)r0 << 7) + ((((ks << 2) + q)) ^ (r0 & 7)) * 8];
            floatx4 s = {0.f, 0.f, 0.f, 0.f};
            __builtin_amdgcn_s_setprio(1);
            #pragma unroll
            for (int ks = 0; ks < 4; ks++) s = MFMA(au[ks], bq[ks], s);
            __builtin_amdgcn_s_setprio(0);
            half4v pk;
            #pragma unroll
            for (int reg = 0; reg < 4; reg++) {
                float p2 = __expf(fminf(s[reg], 11.f));   // masked j -> s-64 -> ~0
                lacc += p2;
                pk[reg] = (f16)p2;
            }
            hv[jb2] = pk;
        }

        // PV (kst = kw): O[i][a] += P[i][j] * U[j][a]; A = own packed scores
        // (pi k-order), B from pi-permuted swizzled Ub[cur].
        {
            h8u u; u.v[0] = hv[0]; u.v[1] = hv[1];
            half8 aP = u.h;
            __builtin_amdgcn_s_setprio(1);
            #pragma unroll
            for (int at = 0; at < 8; at++) {
                int r0 = at * 16 + m;
                half8 bU = *(const half8*)&Ub[cur][((size_t)r0 << 6) + ((((kw << 2) + q)) ^ (r0 & 7)) * 8];
                Oacc[at] = MFMA(aP, bU, Oacc[at]);
            }
            __builtin_amdgcn_s_setprio(0);
        }
        __syncthreads();  // single barrier: drains jt+1 DMA, releases cur
    }

    // ---- epilogue ----
    lacc += __shfl_xor(lacc, 16, 64);
    lacc += __shfl_xor(lacc, 32, 64);
    if (q == 0) lredS[ihw][kw][m] = lacc;
    __syncthreads();
    size_t rbase = hoff * Ln + (size_t)it * 64;
    float* ox = (float*)Us;  // [4][64][32] floats = 32KB
    if (t < 64) {
        float inv = 1.0f / (lredS[t >> 4][0][t & 15] + lredS[t >> 4][1][t & 15]);
        linvS[t] = inv;
        int mk = mask[n * Ln + it * 64 + t];
        rowLinv[rbase + t] = mk ? inv : 0.f;  // i-mask folded for msgj
    }
    if (kw == 1) {
        float* od = ox + ((size_t)ihw * 64 + l) * 32;
        #pragma unroll
        for (int at = 0; at < 8; at++)
            *(floatx4*)(od + at * 4) = Oacc[at];
    }
    __syncthreads();
    if (kw == 0) {
        const float* od = ox + ((size_t)ihw * 64 + l) * 32;
        f16* Mo = Macc + rbase * Dn;
        #pragma unroll
        for (int reg = 0; reg < 4; reg++) {
            int row = ihw * 16 + 4 * q + reg;
            float inv = linvS[row];
            #pragma unroll
            for (int at = 0; at < 8; at++) {
                float v = Oacc[at][reg] + od[at * 4 + reg];
                Mo[(size_t)row * Dn + at * 16 + m] = (f16)(v * inv);
            }
        }
    }
}

// ---------------- msg_j: mirrored 8-wave, register-resident P' --------------
__launch_bounds__(512, 2)
__global__ void msgj_kernel(const f16* __restrict__ Qz, const f16* __restrict__ U,
                            const f16* __restrict__ Vt, const int* __restrict__ mask,
                            const float* __restrict__ rowLinv, f16* __restrict__ Macc) {
    int p = blockIdx.x;              // dispatch order; XCD = p % 8 owns head h
    int h  = p & 7;
    int jt = (p >> 3) & 15;
    int n  = p >> 7;
    int t = threadIdx.x;
    int w = t >> 6, l = t & 63, m = l & 15, q = l >> 4;
    int jhw = w >> 1;  // j-row quarter (16 rows)
    int kw  = w & 1;   // i-half of the reduction

    __shared__ __align__(16) f16 Qs[2][64 * 128];   // Qz i-tile, swizzled
    __shared__ __align__(16) f16 Vb[2][128 * 64];   // Vt slice [b][i'], swizzled
    __shared__ __align__(16) float lvS[2][64];

    size_t hoff = (size_t)(n * Hn + h);

    // resident B-frags: U rows of this wave's 16 j (bias carries j-mask)
    half8 bu[4];
    {
        const f16* ur = U + (hoff * Ln + (size_t)jt * 64 + jhw * 16 + m) * Dn;
        #pragma unroll
        for (int ks = 0; ks < 4; ks++)
            bu[ks] = *(const half8*)(ur + ks * 32 + q * 8);
    }

    floatx4 Oacc[8];
    #pragma unroll
    for (int bt = 0; bt < 8; bt++) Oacc[bt] = (floatx4){0.f, 0.f, 0.f, 0.f};

    // preload it2=0
    issue_tiles8(Qz + (size_t)n * Ln * Dn, Vt + hoff * Dn * Ln, Ln, Qs[0], Vb[0], w, l);
    if (t < 64) lvS[0][t] = rowLinv[hoff * Ln + t];
    __syncthreads();

    for (int it2 = 0; it2 < 16; it2++) {
        int cur = it2 & 1, nxt = cur ^ 1;
        if (it2 + 1 < 16) {
            issue_tiles8(Qz + ((size_t)n * Ln + (size_t)(it2 + 1) * 64) * Dn,
                         Vt + hoff * Dn * Ln + (it2 + 1) * 64, Ln, Qs[nxt], Vb[nxt], w, l);
            if (t < 64) lvS[nxt][t] = rowLinv[hoff * Ln + (it2 + 1) * 64 + t];
        }
        // scores S[i][j] for ibt = 2kw+ib2, this wave's 16 j (mask in bu bias)
        half4v hv[2];
        #pragma unroll
        for (int ib2 = 0; ib2 < 2; ib2++) {
            int ibt = kw * 2 + ib2;
            int r0 = ibt * 16 + m;
            half8 aq2[4];
            #pragma unroll
            for (int ks = 0; ks < 4; ks++)
                aq2[ks] = *(const half8*)&Qs[cur][((size_t)r0 << 7) + ((((ks << 2) + q)) ^ (r0 & 7)) * 8];
            float4 lv = *(const float4*)&lvS[cur][ibt * 16 + 4 * q];
            float lv4[4] = { lv.x, lv.y, lv.z, lv.w };
            floatx4 s = {0.f, 0.f, 0.f, 0.f};
            __builtin_amdgcn_s_setprio(1);
            #pragma unroll
            for (int ks = 0; ks < 4; ks++) s = MFMA(aq2[ks], bu[ks], s);
            __builtin_amdgcn_s_setprio(0);
            half4v pk;
            #pragma unroll
            for (int reg = 0; reg < 4; reg++)
                pk[reg] = (f16)(__expf(fminf(s[reg], 11.f)) * lv4[reg]);
            hv[ib2] = pk;
        }

        // PV (kst = kw): O[j][b] += P'[j][i] * V[i][b]
        {
            h8u u; u.v[0] = hv[0]; u.v[1] = hv[1];
            half8 aP = u.h;
            __builtin_amdgcn_s_setprio(1);
            #pragma unroll
            for (int bt = 0; bt < 8; bt++) {
                int r0 = bt * 16 + m;
                half8 bV = *(const half8*)&Vb[cur][((size_t)r0 << 6) + ((((kw << 2) + q)) ^ (r0 & 7)) * 8];
                Oacc[bt] = MFMA(aP, bV, Oacc[bt]);
            }
            __builtin_amdgcn_s_setprio(0);
        }
        __syncthreads();  // single barrier per it2
    }

    // ---- epilogue: pair-reduce Oacc across kw, then RMW Macc ----
    float* ox = (float*)Qs;  // reuse, [4][64][32] floats
    if (kw == 1) {
        float* od = ox + ((size_t)jhw * 64 + l) * 32;
        #pragma unroll
        for (int bt = 0; bt < 8; bt++)
            *(floatx4*)(od + bt * 4) = Oacc[bt];
    }
    __syncthreads();
    if (kw == 0) {
        const float* od = ox + ((size_t)jhw * 64 + l) * 32;
        f16* Mo = Macc + (hoff * Ln + (size_t)jt * 64) * Dn;
        #pragma unroll
        for (int reg = 0; reg < 4; reg++) {
            int row = jhw * 16 + 4 * q + reg;
            #pragma unroll
            for (int bt = 0; bt < 8; bt++) {
                f16* p2 = &Mo[(size_t)row * Dn + bt * 16 + m];
                float v = Oacc[bt][reg] + od[bt * 4 + reg];
                *p2 = (f16)((float)*p2 + v);
            }
        }
    }
}

// ---------------- fused combine (+softmax | +mask) --------------------------
__global__ void combine_kernel(const float* __restrict__ x, const f16* __restrict__ Macc,
                               const int* __restrict__ mask, float* __restrict__ out,
                               f16* __restrict__ Qzh, int do_softmax, int do_mask) {
    int row = blockIdx.x;           // B*L rows
    int t = threadIdx.x;            // 0..127
    __shared__ float red[2];
    int n = row >> 10;
    float acc = x[(size_t)row * Dn + t];
    const f16* mp = Macc + (size_t)n * Hn * Ln * Dn + (size_t)(row & 1023) * Dn + t;
    #pragma unroll
    for (int h = 0; h < Hn; h++) acc += (float)mp[(size_t)h * Ln * Dn];
    float o = acc;
    if (do_mask && mask[row] == 0) o = 0.f;
    out[(size_t)row * Dn + t] = o;
    if (do_softmax) {
        float m = acc;
        #pragma unroll
        for (int off = 1; off < 64; off <<= 1) m = fmaxf(m, __shfl_xor(m, off, 64));
        if ((t & 63) == 0) red[t >> 6] = m;
        __syncthreads();
        m = fmaxf(red[0], red[1]);
        float e = __expf(acc - m);
        float s = e;
        #pragma unroll
        for (int off = 1; off < 64; off <<= 1) s += __shfl_xor(s, off, 64);
        __syncthreads();
        if ((t & 63) == 0) red[t >> 6] = s;
        __syncthreads();
        s = red[0] + red[1];
        Qzh[(size_t)row * Dn + t] = (f16)(e / s);
    }
}

extern "C" void kernel_launch(void* const* d_in, const int* in_sizes, int n_in,
                              void* d_out, int out_size, void* d_ws, size_t ws_size,
                              hipStream_t stream) {
    const float* x       = (const float*)d_in[0];
    const int*   mask    = (const int*)d_in[1];
    const float* ternary = (const float*)d_in[2];
    const float* global_ = (const float*)d_in[3];
    float* out = (float*)d_out;
    (void)ws_size; (void)n_in; (void)in_sizes; (void)out_size;

    char* ws = (char*)d_ws;
    size_t o = 0;
    f16* Qzh = (f16*)(ws + o); o += (size_t)Bn * Ln * Dn * 2;
    f16* U   = (f16*)(ws + o); o += (size_t)Bn * Hn * Ln * Dn * 2;
    f16* Ut  = (f16*)(ws + o); o += (size_t)Bn * Hn * Ln * Dn * 2;
    f16* Vt  = (f16*)(ws + o); o += (size_t)Bn * Hn * Ln * Dn * 2;
    f16* TpA = (f16*)(ws + o); o += (size_t)Hn * Dn * Dn * 2;
    f16* TpB = (f16*)(ws + o); o += (size_t)Hn * Dn * Dn * 2;
    f16* GpA = (f16*)(ws + o); o += (size_t)Hn * Gn * Dn * 2;
    f16* Gpt = (f16*)(ws + o); o += (size_t)Hn * Dn * Gn * 2;
    float* rowLinv = (float*)(ws + o); o += (size_t)Bn * Hn * Ln * 4;
    f16* Macc = (f16*)(ws + o); o += (size_t)Bn * Hn * Ln * Dn * 2;

    repack_kernel<<<(Dn * Dn * Hn + 255) / 256, 256, 0, stream>>>(ternary, global_, TpA, TpB, GpA, Gpt);
    softmax_rows_kernel<<<Bn * Ln, 128, 0, stream>>>(x, Qzh);

    for (int it = 0; it < NITERS; it++) {
        uv_kernel<<<dim3(Ln / 64 * Hn * Bn), 256, 0, stream>>>(Qzh, TpA, TpB, mask, U, Ut, Vt);
        msgi_kernel<<<dim3(Ln / 64 * Hn * Bn), 512, 0, stream>>>(Qzh, U, Ut, GpA, Gpt, mask, Macc, rowLinv);
        msgj_kernel<<<dim3(Ln / 64 * Hn * Bn), 512, 0, stream>>>(Qzh, U, Vt, mask, rowLinv, Macc);
        combine_kernel<<<Bn * Ln, 128, 0, stream>>>(x, Macc, mask, out, Qzh,
                                                    (it < NITERS - 1) ? 1 : 0,
                                                    (it == NITERS - 1) ? 1 : 0);
    }
}